// Round 8
// baseline (151.422 us; speedup 1.0000x reference)
//
#include <hip/hip_runtime.h>

typedef __bf16 bf16x8 __attribute__((ext_vector_type(8)));
typedef float f32x4 __attribute__((ext_vector_type(4)));
typedef unsigned int uint4v __attribute__((ext_vector_type(4)));
typedef unsigned int uint2v __attribute__((ext_vector_type(2)));

__device__ __forceinline__ unsigned short f2bf(float f) {
  union { float f; unsigned int u; } v; v.f = f;
  unsigned int u = v.u;
  u += 0x7FFFu + ((u >> 16) & 1u);   // RTNE
  return (unsigned short)(u >> 16);
}

__device__ __forceinline__ unsigned int pack2bf(float a, float b) {
  return (unsigned int)f2bf(a) | ((unsigned int)f2bf(b) << 16);
}

// truncating pack (low = a, high = b) in ONE v_perm_b32; downward bias
// cancels between softmax numerator and denominator.
__device__ __forceinline__ unsigned int packtrunc(float a, float b) {
  return __builtin_amdgcn_perm(__float_as_uint(b), __float_as_uint(a),
                               0x07060302u);
}

// ---------------------------------------------------------------------------
// Convert weight matrices to bf16. Wq scaled by qscale = 1/8*log2e.
// ---------------------------------------------------------------------------
__global__ __launch_bounds__(256) void convert_w(
    const float* wq, const float* wk, const float* wv, const float* wo,
    unsigned short* wqc, unsigned short* wkc, unsigned short* wvc,
    unsigned short* woc, float qscale)
{
  const float* src; unsigned short* dst; float sc = 1.f;
  switch (blockIdx.y) {
    case 0: src = wq; dst = wqc; sc = qscale; break;
    case 1: src = wk; dst = wkc; break;
    case 2: src = wv; dst = wvc; break;
    default: src = wo; dst = woc; break;
  }
  int idx = (blockIdx.x * 256 + threadIdx.x) * 8;
  f32x4 a = *(const f32x4*)(src + idx);
  f32x4 b = *(const f32x4*)(src + idx + 4);
  uint4v p;
  p.x = pack2bf(a.x * sc, a.y * sc);
  p.y = pack2bf(a.z * sc, a.w * sc);
  p.z = pack2bf(b.x * sc, b.y * sc);
  p.w = pack2bf(b.z * sc, b.w * sc);
  *(uint4v*)(dst + idx) = p;
}

// ---------------------------------------------------------------------------
// GEMM core, LDS ping-pong (ONE barrier per K-step): 64x128 tile, BK=32,
// 4 waves, register prefetch one step ahead. Optional inline fp32->bf16 A.
// Safety of single barrier: writers of buf at step kt come after the step
// kt-1 barrier, and the last readers of buf (step kt-2 compute) drained
// their LDS reads before entering that same barrier.
// OUT: 0 = bf16 row-major, 1 = f32 row-major, 2 = bf16 transposed to
//      Vt[bh][d][s] via LDS round-trip (epilogue only).
// ---------------------------------------------------------------------------
template<int OUT, bool AF32>
__device__ __forceinline__ void gemm_core(
    const void* __restrict__ Ap, const unsigned short* __restrict__ W,
    const float* __restrict__ bias, void* __restrict__ Cp,
    float bscale, int mbase, int nbase)
{
  __shared__ union {
    struct { unsigned short As[2][64][40]; unsigned short Bs[2][128][40]; } t;
    unsigned short Cs[128][72];
  } u;

  const int tid  = threadIdx.x;
  const int wave = tid >> 6, lane = tid & 63;
  const int lrow = lane & 15, lgrp = lane >> 4;
  const int ar = tid >> 2, ac = (tid & 3) * 8;

  const unsigned short* Bg0 = W + (size_t)(nbase + ar) * 512 + ac;
  const unsigned short* Bg1 = W + (size_t)(nbase + ar + 64) * 512 + ac;

  f32x4 acc[4][2];
#pragma unroll
  for (int i = 0; i < 4; i++)
#pragma unroll
    for (int j = 0; j < 2; j++) acc[i][j] = (f32x4){0.f, 0.f, 0.f, 0.f};

  const unsigned short* Ab = (const unsigned short*)Ap;
  const float*          Af = (const float*)Ap;
  uint4v pA; f32x4 pAf0, pAf1;
  if constexpr (AF32) {
    const float* base = Af + (size_t)(mbase + ar) * 512 + ac;
    pAf0 = *(const f32x4*)(base);
    pAf1 = *(const f32x4*)(base + 4);
  } else {
    pA = *(const uint4v*)(Ab + (size_t)(mbase + ar) * 512 + ac);
  }
  uint4v pB0 = *(const uint4v*)Bg0;
  uint4v pB1 = *(const uint4v*)Bg1;

  for (int kt = 0; kt < 512; kt += 32) {
    const int buf = (kt >> 5) & 1;
    if constexpr (AF32) {
      uint4v w;
      w.x = pack2bf(pAf0.x, pAf0.y); w.y = pack2bf(pAf0.z, pAf0.w);
      w.z = pack2bf(pAf1.x, pAf1.y); w.w = pack2bf(pAf1.z, pAf1.w);
      *(uint4v*)&u.t.As[buf][ar][ac] = w;
    } else {
      *(uint4v*)&u.t.As[buf][ar][ac] = pA;
    }
    *(uint4v*)&u.t.Bs[buf][ar][ac]      = pB0;
    *(uint4v*)&u.t.Bs[buf][ar + 64][ac] = pB1;
    if (kt + 32 < 512) {                  // prefetch next K-step
      if constexpr (AF32) {
        const float* base = Af + (size_t)(mbase + ar) * 512 + ac + kt + 32;
        pAf0 = *(const f32x4*)(base);
        pAf1 = *(const f32x4*)(base + 4);
      } else {
        pA = *(const uint4v*)(Ab + (size_t)(mbase + ar) * 512 + ac + kt + 32);
      }
      pB0 = *(const uint4v*)(Bg0 + kt + 32);
      pB1 = *(const uint4v*)(Bg1 + kt + 32);
    }
    __syncthreads();                      // single barrier per step
    bf16x8 a[4], b[2];
#pragma unroll
    for (int mi = 0; mi < 4; mi++)
      a[mi] = *(const bf16x8*)&u.t.As[buf][mi * 16 + lrow][lgrp * 8];
#pragma unroll
    for (int ni = 0; ni < 2; ni++)
      b[ni] = *(const bf16x8*)&u.t.Bs[buf][wave * 32 + ni * 16 + lrow][lgrp * 8];
#pragma unroll
    for (int mi = 0; mi < 4; mi++)
#pragma unroll
      for (int ni = 0; ni < 2; ni++)
        acc[mi][ni] = __builtin_amdgcn_mfma_f32_16x16x32_bf16(
            a[mi], b[ni], acc[mi][ni], 0, 0, 0);
  }

  if constexpr (OUT == 2) {
    __syncthreads();   // Cs aliases As/Bs — drain last frag reads
#pragma unroll
    for (int ni = 0; ni < 2; ni++) {
      int col_l = wave * 32 + ni * 16 + lrow;
      float bv = bias[nbase + col_l];
#pragma unroll
      for (int mi = 0; mi < 4; mi++) {
        int row_l = mi * 16 + lgrp * 4;
#pragma unroll
        for (int r = 0; r < 4; r++)
          u.Cs[col_l][row_l + r] = f2bf(acc[mi][ni][r] + bv);
      }
    }
    __syncthreads();
    const int bb = mbase >> 11, s_base = mbase & 2047;
    unsigned short* Vt = (unsigned short*)Cp;
#pragma unroll
    for (int ks = 0; ks < 4; ks++) {
      int seg = tid + ks * 256;
      int c = seg >> 3, r0 = (seg & 7) * 8;
      uint4v val = *(const uint4v*)&u.Cs[c][r0];
      int n = nbase + c, hh = n >> 6, d = n & 63;
      *(uint4v*)(Vt + ((size_t)(bb * 8 + hh) * 64 + d) * 2048 + s_base + r0) = val;
    }
  } else {
#pragma unroll
    for (int ni = 0; ni < 2; ni++) {
      int col = nbase + wave * 32 + ni * 16 + lrow;
      float bv = bias[col] * bscale;
#pragma unroll
      for (int mi = 0; mi < 4; mi++) {
        int row0 = mbase + mi * 16 + lgrp * 4;
#pragma unroll
        for (int r = 0; r < 4; r++) {
          float val = acc[mi][ni][r] + bv;
          if constexpr (OUT == 0)
            ((unsigned short*)Cp)[(size_t)(row0 + r) * 512 + col] = f2bf(val);
          else
            ((float*)Cp)[(size_t)(row0 + r) * 512 + col] = val;
        }
      }
    }
  }
}

__global__ __launch_bounds__(256) void qkv_gemm(
    const float* q, const float* k, const float* v,
    const unsigned short* wqc, const unsigned short* wkc,
    const unsigned short* wvc,
    const float* bq, const float* bk, const float* bv,
    unsigned short* Qb, unsigned short* Kb, unsigned short* Vt, float qscale)
{
  const int z = blockIdx.z;
  const int mb = blockIdx.y * 64, nb = blockIdx.x * 128;
  if (z == 2)      gemm_core<2, true>(v, wvc, bv, Vt, 1.f, mb, nb);
  else if (z == 0) gemm_core<0, true>(q, wqc, bq, Qb, qscale, mb, nb);
  else             gemm_core<0, true>(k, wkc, bk, Kb, 1.f, mb, nb);
}

// ---------------------------------------------------------------------------
// Output GEMM: 64x64 tile -> grid 512 (2 blocks/CU), LDS ping-pong, one
// barrier per K-step. Wave w owns n-cols w*16..+15, all 64 m-rows.
// ---------------------------------------------------------------------------
__global__ __launch_bounds__(256) void out_gemm(
    const unsigned short* ctx, const unsigned short* woc,
    const float* bo, float* out)
{
  __shared__ unsigned short As[2][64][40];
  __shared__ unsigned short Bs[2][64][40];

  const int tid  = threadIdx.x;
  const int wave = tid >> 6, lane = tid & 63;
  const int lrow = lane & 15, lgrp = lane >> 4;
  const int mbase = blockIdx.y * 64, nbase = blockIdx.x * 64;
  const int ar = tid >> 2, ac = (tid & 3) * 8;

  const unsigned short* Ag = ctx + (size_t)(mbase + ar) * 512 + ac;
  const unsigned short* Bg = woc + (size_t)(nbase + ar) * 512 + ac;

  f32x4 acc[4];
#pragma unroll
  for (int i = 0; i < 4; i++) acc[i] = (f32x4){0.f, 0.f, 0.f, 0.f};

  uint4v pA = *(const uint4v*)Ag;
  uint4v pB = *(const uint4v*)Bg;

  for (int kt = 0; kt < 512; kt += 32) {
    const int buf = (kt >> 5) & 1;
    *(uint4v*)&As[buf][ar][ac] = pA;
    *(uint4v*)&Bs[buf][ar][ac] = pB;
    if (kt + 32 < 512) {
      pA = *(const uint4v*)(Ag + kt + 32);
      pB = *(const uint4v*)(Bg + kt + 32);
    }
    __syncthreads();
    bf16x8 a[4];
#pragma unroll
    for (int mi = 0; mi < 4; mi++)
      a[mi] = *(const bf16x8*)&As[buf][mi * 16 + lrow][lgrp * 8];
    bf16x8 b = *(const bf16x8*)&Bs[buf][wave * 16 + lrow][lgrp * 8];
#pragma unroll
    for (int mi = 0; mi < 4; mi++)
      acc[mi] = __builtin_amdgcn_mfma_f32_16x16x32_bf16(a[mi], b, acc[mi], 0, 0, 0);
  }

  int col = nbase + wave * 16 + lrow;
  float bv = bo[col];
#pragma unroll
  for (int mi = 0; mi < 4; mi++) {
    int row0 = mbase + mi * 16 + lgrp * 4;
#pragma unroll
    for (int r = 0; r < 4; r++)
      out[(size_t)(row0 + r) * 512 + col] = acc[mi][r] + bv;
  }
}

// ---------------------------------------------------------------------------
// Flash attention v7: v6 structure + split-phase software pipeline.
//  - Ks double-buffered: K_{it+1} written during phase B into the idle
//    buffer (no reader until next iter). V written at iter start (its
//    readers, PV of it-1, drained at the previous end-of-iter barrier).
//  - Phase A (QK + exp2 + P store) overlaps V staging; phase B (PV)
//    overlaps K staging. Barriers no longer serialize stage->compute.
//  - l = sum(p) by MFMA via ones-tile; packtrunc P pack; exp2-domain
//    softmax with no max tracking.
// LDS = Ks 2x18.9K + Vs(80x138) 21.6K + Ps 19K = 77.6 KB -> 2 blocks/CU.
// ---------------------------------------------------------------------------
__global__ __launch_bounds__(256) void attn_kernel(
    const unsigned short* Qb, const unsigned short* Kb,
    const unsigned short* Vt, unsigned short* ctx)
{
  __shared__ unsigned short Ks[2][128][74];  // [buf][slot][d]
  __shared__ unsigned short Vs[80][138];     // [d][kh*64+local]; rows 64..79=1
  __shared__ unsigned short Ps[2][64][76];   // [kh][qrow][local]; Q at start

  const int tid  = threadIdx.x;
  const int wave = tid >> 6, lane = tid & 63;
  const int lrow = lane & 15, lgrp = lane >> 4;
  const int qh = wave >> 1, kh = wave & 1;
  const int bh = blockIdx.y, b = bh >> 3, h = bh & 7;
  const int qbase = blockIdx.x * 64;

  const unsigned short* Qg  = Qb + (size_t)(b * 2048 + qbase) * 512 + h * 64;
  const unsigned short* Kg  = Kb + (size_t)(b * 2048) * 512 + h * 64;
  const unsigned short* Vtg = Vt + (size_t)bh * 64 * 2048;

  // stage Q (64x64) into Ps[0]; ones-rows of Vs (once)
#pragma unroll
  for (int i = 0; i < 2; i++) {
    int seg = tid + i * 256;
    int row = seg >> 3, c0 = (seg & 7) * 8;
    *(uint4v*)&Ps[0][row][c0] = *(const uint4v*)(Qg + (size_t)row * 512 + c0);
  }
  {
    int row = 64 + (tid >> 4), c0 = (tid & 15) * 8;
    unsigned int one2 = 0x3F803F80u;
    *(uint4v*)&Vs[row][c0] = (uint4v){one2, one2, one2, one2};
  }
  __syncthreads();
  bf16x8 qf[2][2];
#pragma unroll
  for (int mi = 0; mi < 2; mi++)
#pragma unroll
    for (int c = 0; c < 2; c++)
      qf[mi][c] = *(const bf16x8*)&Ps[0][qh * 32 + mi * 16 + lrow][c * 32 + lgrp * 8];

  // staging coords
  const int s0 = tid >> 3, kc_ = (tid & 7) * 8;       // K slots s0+32i
  const int krow0 = ((s0 & 15) << 3) | (s0 >> 4);     // global key row, +2/i
  const int vd_ = tid >> 4, vcl = (tid & 15);         // V d-rows vd_+16i

  f32x4 oacc[2][5];                       // [mi][dt]; dt==4 is the l-column
#pragma unroll
  for (int mi = 0; mi < 2; mi++)
#pragma unroll
    for (int d = 0; d < 5; d++) oacc[mi][d] = (f32x4){0.f, 0.f, 0.f, 0.f};

  // initial fill: K0 -> Ks[0], V0 -> Vs; then preload K1, V1 into regs
  uint4v kr[4], vr[4];
#pragma unroll
  for (int i = 0; i < 4; i++) {
    kr[i] = *(const uint4v*)(Kg + (size_t)(krow0 + 2 * i) * 512 + kc_);
    vr[i] = *(const uint4v*)(Vtg + (size_t)(vd_ + 16 * i) * 2048 + vcl * 8);
  }
#pragma unroll
  for (int i = 0; i < 4; i++) {
    *(uint4v*)&Ks[0][s0 + 32 * i][kc_] = kr[i];
    *(uint2v*)&Vs[vd_ + 16 * i][vcl * 4]      = (uint2v){vr[i].x, vr[i].y};
    *(uint2v*)&Vs[vd_ + 16 * i][64 + vcl * 4] = (uint2v){vr[i].z, vr[i].w};
  }
#pragma unroll
  for (int i = 0; i < 4; i++) {
    kr[i] = *(const uint4v*)(Kg + (size_t)(128 + krow0 + 2 * i) * 512 + kc_);
    vr[i] = *(const uint4v*)(Vtg + (size_t)(vd_ + 16 * i) * 2048 + 128 + vcl * 8);
  }
  __syncthreads();

  for (int it = 0; it < 16; ++it) {
    const int buf = it & 1;
    // write V_it (readers PV_{it-1} drained at prior end barrier);
    // overlapped with phase A below
    if (it > 0) {
#pragma unroll
      for (int i = 0; i < 4; i++) {
        *(uint2v*)&Vs[vd_ + 16 * i][vcl * 4]      = (uint2v){vr[i].x, vr[i].y};
        *(uint2v*)&Vs[vd_ + 16 * i][64 + vcl * 4] = (uint2v){vr[i].z, vr[i].w};
      }
      if (it < 15) {
        const int key0 = (it + 1) * 128;
#pragma unroll
        for (int i = 0; i < 4; i++)
          vr[i] = *(const uint4v*)(Vtg + (size_t)(vd_ + 16 * i) * 2048 + key0 + vcl * 8);
      }
    }

    // ---- phase A: S quarter + exp2 + P store (reads Ks[buf], wave-priv Ps)
    f32x4 sacc[2][4];
#pragma unroll
    for (int mi = 0; mi < 2; mi++)
#pragma unroll
      for (int ni = 0; ni < 4; ni++) sacc[mi][ni] = (f32x4){0.f, 0.f, 0.f, 0.f};
#pragma unroll
    for (int ni = 0; ni < 4; ni++) {
      const int t = 4 * kh + ni;
      bf16x8 k0 = *(const bf16x8*)&Ks[buf][t * 16 + lrow][lgrp * 8];
      bf16x8 k1 = *(const bf16x8*)&Ks[buf][t * 16 + lrow][32 + lgrp * 8];
#pragma unroll
      for (int mi = 0; mi < 2; mi++) {
        sacc[mi][ni] = __builtin_amdgcn_mfma_f32_16x16x32_bf16(qf[mi][0], k0, sacc[mi][ni], 0, 0, 0);
        sacc[mi][ni] = __builtin_amdgcn_mfma_f32_16x16x32_bf16(qf[mi][1], k1, sacc[mi][ni], 0, 0, 0);
      }
    }
#pragma unroll
    for (int mi = 0; mi < 2; mi++)
#pragma unroll
      for (int ni = 0; ni < 4; ni++)
#pragma unroll
        for (int r = 0; r < 4; r++)
          sacc[mi][ni][r] = __builtin_amdgcn_exp2f(sacc[mi][ni][r]);
#pragma unroll
    for (int mi = 0; mi < 2; mi++)
#pragma unroll
      for (int r = 0; r < 4; r++) {
        uint2v pk;
        pk.x = packtrunc(sacc[mi][0][r], sacc[mi][1][r]);
        pk.y = packtrunc(sacc[mi][2][r], sacc[mi][3][r]);
        *(uint2v*)&Ps[kh][qh * 32 + mi * 16 + lgrp * 4 + r][lrow * 4] = pk;
      }

    __syncthreads();   // V_it writes visible before PV

    // ---- phase B: O += P V ; overlapped K_{it+1} staging into idle buffer
#pragma unroll
    for (int ks = 0; ks < 2; ks++) {
      bf16x8 pa[2];
#pragma unroll
      for (int mi = 0; mi < 2; mi++)
        pa[mi] = *(const bf16x8*)&Ps[kh][qh * 32 + mi * 16 + lrow][ks * 32 + lgrp * 8];
#pragma unroll
      for (int dt = 0; dt < 5; dt++) {
        bf16x8 vb = *(const bf16x8*)&Vs[dt * 16 + lrow][kh * 64 + ks * 32 + lgrp * 8];
#pragma unroll
        for (int mi = 0; mi < 2; mi++)
          oacc[mi][dt] = __builtin_amdgcn_mfma_f32_16x16x32_bf16(pa[mi], vb, oacc[mi][dt], 0, 0, 0);
      }
    }
    if (it < 15) {
#pragma unroll
      for (int i = 0; i < 4; i++)
        *(uint4v*)&Ks[1 - buf][s0 + 32 * i][kc_] = kr[i];
      if (it < 14) {
        const int key0 = (it + 2) * 128;
#pragma unroll
        for (int i = 0; i < 4; i++)
          kr[i] = *(const uint4v*)(Kg + (size_t)(key0 + krow0 + 2 * i) * 512 + kc_);
      }
    }
    __syncthreads();   // PV reads + K writes drained
  }

  // cross-wave (kh) merge of O and l through dead Ks/Vs space
  float* Obuf = (float*)&Ks[0][0][0];     // 64 x 68 fp32 = 17.4 KB
  float* Lbuf = (float*)&Vs[0][0];        // 64 fp32
  if (kh == 1) {
#pragma unroll
    for (int mi = 0; mi < 2; mi++)
#pragma unroll
      for (int r = 0; r < 4; r++) {
        int row = qh * 32 + mi * 16 + lgrp * 4 + r;
#pragma unroll
        for (int dt = 0; dt < 4; dt++)
          Obuf[row * 68 + dt * 16 + lrow] = oacc[mi][dt][r];
        if (lrow == 0) Lbuf[row] = oacc[mi][4][r];
      }
  }
  __syncthreads();
  if (kh == 0) {
    unsigned short* Cg = ctx + (size_t)(b * 2048 + qbase) * 512 + h * 64;
#pragma unroll
    for (int mi = 0; mi < 2; mi++)
#pragma unroll
      for (int r = 0; r < 4; r++) {
        int row = qh * 32 + mi * 16 + lgrp * 4 + r;
        float inv = 1.0f / (oacc[mi][4][r] + Lbuf[row]);
#pragma unroll
        for (int dt = 0; dt < 4; dt++) {
          float val = (oacc[mi][dt][r] + Obuf[row * 68 + dt * 16 + lrow]) * inv;
          Cg[(size_t)row * 512 + dt * 16 + lrow] = f2bf(val);
        }
      }
  }
}

extern "C" void kernel_launch(void* const* d_in, const int* in_sizes, int n_in,
                              void* d_out, int out_size, void* d_ws, size_t ws_size,
                              hipStream_t stream)
{
  const float* q  = (const float*)d_in[0];
  const float* k  = (const float*)d_in[1];
  const float* v  = (const float*)d_in[2];
  const float* Wq = (const float*)d_in[3];
  const float* bq = (const float*)d_in[4];
  const float* Wk = (const float*)d_in[5];
  const float* bk = (const float*)d_in[6];
  const float* Wv = (const float*)d_in[7];
  const float* bv = (const float*)d_in[8];
  const float* Wo = (const float*)d_in[9];
  const float* bo = (const float*)d_in[10];
  float* out = (float*)d_out;

  unsigned short* wqc = (unsigned short*)d_ws;
  unsigned short* wkc = wqc + (1 << 18);
  unsigned short* wvc = wkc + (1 << 18);
  unsigned short* woc = wvc + (1 << 18);
  unsigned short* Qb  = woc + (1 << 18);
  unsigned short* Kb  = Qb  + (1 << 21);
  unsigned short* Vt  = Kb  + (1 << 21);
  unsigned short* Cb  = Vt  + (1 << 21);

  const float qscale = 0.125f * 1.44269504088896340736f;  // 1/sqrt(64)*log2e

  convert_w<<<dim3(128, 4), 256, 0, stream>>>(
      Wq, Wk, Wv, Wo, wqc, wkc, wvc, woc, qscale);
  qkv_gemm<<<dim3(4, 64, 3), 256, 0, stream>>>(
      q, k, v, wqc, wkc, wvc, bq, bk, bv, Qb, Kb, Vt, qscale);
  attn_kernel<<<dim3(32, 16), 256, 0, stream>>>(Qb, Kb, Vt, Cb);
  out_gemm<<<dim3(8, 64), 256, 0, stream>>>(Cb, woc, bo, out);
}

// Round 9
// 144.944 us; speedup vs baseline: 1.0447x; 1.0447x over previous
//
#include <hip/hip_runtime.h>

typedef __bf16 bf16x8 __attribute__((ext_vector_type(8)));
typedef float f32x4 __attribute__((ext_vector_type(4)));
typedef unsigned int uint4v __attribute__((ext_vector_type(4)));
typedef unsigned int uint2v __attribute__((ext_vector_type(2)));

__device__ __forceinline__ unsigned short f2bf(float f) {
  union { float f; unsigned int u; } v; v.f = f;
  unsigned int u = v.u;
  u += 0x7FFFu + ((u >> 16) & 1u);   // RTNE
  return (unsigned short)(u >> 16);
}

__device__ __forceinline__ unsigned int pack2bf(float a, float b) {
  return (unsigned int)f2bf(a) | ((unsigned int)f2bf(b) << 16);
}

// truncating pack (low = a, high = b) in ONE v_perm_b32; downward bias
// cancels between softmax numerator and denominator.
__device__ __forceinline__ unsigned int packtrunc(float a, float b) {
  return __builtin_amdgcn_perm(__float_as_uint(b), __float_as_uint(a),
                               0x07060302u);
}

__device__ __forceinline__ bf16x8 as_bf(uint4v u) {
  union { uint4v u; bf16x8 b; } c; c.u = u; return c.b;
}

// ---------------------------------------------------------------------------
// Convert weight matrices to bf16. Wq scaled by qscale = 1/8*log2e.
// ---------------------------------------------------------------------------
__global__ __launch_bounds__(256) void convert_w(
    const float* wq, const float* wk, const float* wv, const float* wo,
    unsigned short* wqc, unsigned short* wkc, unsigned short* wvc,
    unsigned short* woc, float qscale)
{
  const float* src; unsigned short* dst; float sc = 1.f;
  switch (blockIdx.y) {
    case 0: src = wq; dst = wqc; sc = qscale; break;
    case 1: src = wk; dst = wkc; break;
    case 2: src = wv; dst = wvc; break;
    default: src = wo; dst = woc; break;
  }
  int idx = (blockIdx.x * 256 + threadIdx.x) * 8;
  f32x4 a = *(const f32x4*)(src + idx);
  f32x4 b = *(const f32x4*)(src + idx + 4);
  uint4v p;
  p.x = pack2bf(a.x * sc, a.y * sc);
  p.y = pack2bf(a.z * sc, a.w * sc);
  p.z = pack2bf(b.x * sc, b.y * sc);
  p.w = pack2bf(b.z * sc, b.w * sc);
  *(uint4v*)(dst + idx) = p;
}

// ---------------------------------------------------------------------------
// GEMM core (R8): 64x128 tile, BK=32, LDS ping-pong (one barrier/step),
// register prefetch, optional inline fp32->bf16 A conversion.
// OUT: 0 = bf16 row-major, 1 = f32 row-major, 2 = bf16 transposed to
//      Vt[bh][d][sigma(s)] — the key axis is stored PERMUTED (low-5-bit
//      shuffle pos[4:3]=s[3:2], pos[2]=s[4], pos[1:0]=s[1:0]) so the
//      attention kernel's PV B-operand (P^T straight out of QK^T C-regs)
//      contracts against V columns with zero P LDS round-trip.
// ---------------------------------------------------------------------------
template<int OUT, bool AF32>
__device__ __forceinline__ void gemm_core(
    const void* __restrict__ Ap, const unsigned short* __restrict__ W,
    const float* __restrict__ bias, void* __restrict__ Cp,
    float bscale, int mbase, int nbase)
{
  __shared__ union {
    struct { unsigned short As[2][64][40]; unsigned short Bs[2][128][40]; } t;
    unsigned short Cs[128][72];
  } u;

  const int tid  = threadIdx.x;
  const int wave = tid >> 6, lane = tid & 63;
  const int lrow = lane & 15, lgrp = lane >> 4;
  const int ar = tid >> 2, ac = (tid & 3) * 8;

  const unsigned short* Bg0 = W + (size_t)(nbase + ar) * 512 + ac;
  const unsigned short* Bg1 = W + (size_t)(nbase + ar + 64) * 512 + ac;

  f32x4 acc[4][2];
#pragma unroll
  for (int i = 0; i < 4; i++)
#pragma unroll
    for (int j = 0; j < 2; j++) acc[i][j] = (f32x4){0.f, 0.f, 0.f, 0.f};

  const unsigned short* Ab = (const unsigned short*)Ap;
  const float*          Af = (const float*)Ap;
  uint4v pA; f32x4 pAf0, pAf1;
  if constexpr (AF32) {
    const float* base = Af + (size_t)(mbase + ar) * 512 + ac;
    pAf0 = *(const f32x4*)(base);
    pAf1 = *(const f32x4*)(base + 4);
  } else {
    pA = *(const uint4v*)(Ab + (size_t)(mbase + ar) * 512 + ac);
  }
  uint4v pB0 = *(const uint4v*)Bg0;
  uint4v pB1 = *(const uint4v*)Bg1;

  for (int kt = 0; kt < 512; kt += 32) {
    const int buf = (kt >> 5) & 1;
    if constexpr (AF32) {
      uint4v w;
      w.x = pack2bf(pAf0.x, pAf0.y); w.y = pack2bf(pAf0.z, pAf0.w);
      w.z = pack2bf(pAf1.x, pAf1.y); w.w = pack2bf(pAf1.z, pAf1.w);
      *(uint4v*)&u.t.As[buf][ar][ac] = w;
    } else {
      *(uint4v*)&u.t.As[buf][ar][ac] = pA;
    }
    *(uint4v*)&u.t.Bs[buf][ar][ac]      = pB0;
    *(uint4v*)&u.t.Bs[buf][ar + 64][ac] = pB1;
    if (kt + 32 < 512) {
      if constexpr (AF32) {
        const float* base = Af + (size_t)(mbase + ar) * 512 + ac + kt + 32;
        pAf0 = *(const f32x4*)(base);
        pAf1 = *(const f32x4*)(base + 4);
      } else {
        pA = *(const uint4v*)(Ab + (size_t)(mbase + ar) * 512 + ac + kt + 32);
      }
      pB0 = *(const uint4v*)(Bg0 + kt + 32);
      pB1 = *(const uint4v*)(Bg1 + kt + 32);
    }
    __syncthreads();
    bf16x8 a[4], b[2];
#pragma unroll
    for (int mi = 0; mi < 4; mi++)
      a[mi] = *(const bf16x8*)&u.t.As[buf][mi * 16 + lrow][lgrp * 8];
#pragma unroll
    for (int ni = 0; ni < 2; ni++)
      b[ni] = *(const bf16x8*)&u.t.Bs[buf][wave * 32 + ni * 16 + lrow][lgrp * 8];
#pragma unroll
    for (int mi = 0; mi < 4; mi++)
#pragma unroll
      for (int ni = 0; ni < 2; ni++)
        acc[mi][ni] = __builtin_amdgcn_mfma_f32_16x16x32_bf16(
            a[mi], b[ni], acc[mi][ni], 0, 0, 0);
  }

  if constexpr (OUT == 2) {
    __syncthreads();   // Cs aliases As/Bs — drain last frag reads
#pragma unroll
    for (int ni = 0; ni < 2; ni++) {
      int col_l = wave * 32 + ni * 16 + lrow;
      float bv = bias[nbase + col_l];
#pragma unroll
      for (int mi = 0; mi < 4; mi++) {
        int row_l = mi * 16 + lgrp * 4;
#pragma unroll
        for (int r = 0; r < 4; r++)
          u.Cs[col_l][row_l + r] = f2bf(acc[mi][ni][r] + bv);
      }
    }
    __syncthreads();
    const int bb = mbase >> 11, s_base = mbase & 2047;
    unsigned short* Vt = (unsigned short*)Cp;
#pragma unroll
    for (int ks = 0; ks < 4; ks++) {
      int seg = tid + ks * 256;
      int c = seg >> 3, r0 = (seg & 7) * 8;
      uint4v val = *(const uint4v*)&u.Cs[c][r0];
      int n = nbase + c, hh = n >> 6, d = n & 63;
      // permuted key placement: keys sr..sr+3 -> P0.., sr+4..sr+7 -> P0+8..
      int sr = s_base + r0;
      int P0 = (sr & ~31) | (((sr >> 3) & 1) << 4) | (((sr >> 4) & 1) << 2);
      unsigned short* dst = Vt + ((size_t)(bb * 8 + hh) * 64 + d) * 2048;
      *(uint2v*)(dst + P0)     = (uint2v){val.x, val.y};
      *(uint2v*)(dst + P0 + 8) = (uint2v){val.z, val.w};
    }
  } else {
#pragma unroll
    for (int ni = 0; ni < 2; ni++) {
      int col = nbase + wave * 32 + ni * 16 + lrow;
      float bv = bias[col] * bscale;
#pragma unroll
      for (int mi = 0; mi < 4; mi++) {
        int row0 = mbase + mi * 16 + lgrp * 4;
#pragma unroll
        for (int r = 0; r < 4; r++) {
          float val = acc[mi][ni][r] + bv;
          if constexpr (OUT == 0)
            ((unsigned short*)Cp)[(size_t)(row0 + r) * 512 + col] = f2bf(val);
          else
            ((float*)Cp)[(size_t)(row0 + r) * 512 + col] = val;
        }
      }
    }
  }
}

__global__ __launch_bounds__(256) void qkv_gemm(
    const float* q, const float* k, const float* v,
    const unsigned short* wqc, const unsigned short* wkc,
    const unsigned short* wvc,
    const float* bq, const float* bk, const float* bv,
    unsigned short* Qb, unsigned short* Kb, unsigned short* Vt, float qscale)
{
  const int z = blockIdx.z;
  const int mb = blockIdx.y * 64, nb = blockIdx.x * 128;
  if (z == 2)      gemm_core<2, true>(v, wvc, bv, Vt, 1.f, mb, nb);
  else if (z == 0) gemm_core<0, true>(q, wqc, bq, Qb, qscale, mb, nb);
  else             gemm_core<0, true>(k, wkc, bk, Kb, 1.f, mb, nb);
}

// ---------------------------------------------------------------------------
// Output GEMM: 64x64 tile, grid 512, LDS ping-pong (R8).
// ---------------------------------------------------------------------------
__global__ __launch_bounds__(256) void out_gemm(
    const unsigned short* ctx, const unsigned short* woc,
    const float* bo, float* out)
{
  __shared__ unsigned short As[2][64][40];
  __shared__ unsigned short Bs[2][64][40];

  const int tid  = threadIdx.x;
  const int wave = tid >> 6, lane = tid & 63;
  const int lrow = lane & 15, lgrp = lane >> 4;
  const int mbase = blockIdx.y * 64, nbase = blockIdx.x * 64;
  const int ar = tid >> 2, ac = (tid & 3) * 8;

  const unsigned short* Ag = ctx + (size_t)(mbase + ar) * 512 + ac;
  const unsigned short* Bg = woc + (size_t)(nbase + ar) * 512 + ac;

  f32x4 acc[4];
#pragma unroll
  for (int i = 0; i < 4; i++) acc[i] = (f32x4){0.f, 0.f, 0.f, 0.f};

  uint4v pA = *(const uint4v*)Ag;
  uint4v pB = *(const uint4v*)Bg;

  for (int kt = 0; kt < 512; kt += 32) {
    const int buf = (kt >> 5) & 1;
    *(uint4v*)&As[buf][ar][ac] = pA;
    *(uint4v*)&Bs[buf][ar][ac] = pB;
    if (kt + 32 < 512) {
      pA = *(const uint4v*)(Ag + kt + 32);
      pB = *(const uint4v*)(Bg + kt + 32);
    }
    __syncthreads();
    bf16x8 a[4];
#pragma unroll
    for (int mi = 0; mi < 4; mi++)
      a[mi] = *(const bf16x8*)&As[buf][mi * 16 + lrow][lgrp * 8];
    bf16x8 b = *(const bf16x8*)&Bs[buf][wave * 16 + lrow][lgrp * 8];
#pragma unroll
    for (int mi = 0; mi < 4; mi++)
      acc[mi] = __builtin_amdgcn_mfma_f32_16x16x32_bf16(a[mi], b, acc[mi], 0, 0, 0);
  }

  int col = nbase + wave * 16 + lrow;
  float bv = bo[col];
#pragma unroll
  for (int mi = 0; mi < 4; mi++) {
    int row0 = mbase + mi * 16 + lgrp * 4;
#pragma unroll
    for (int r = 0; r < 4; r++)
      out[(size_t)(row0 + r) * 512 + col] = acc[mi][r] + bv;
  }
}

// ---------------------------------------------------------------------------
// Flash attention v8: operand-swapped, ZERO P LDS round-trip.
//  - S^T = K*Q^T (A=K natural rows, B=Q persistent register frags). C-layout:
//    col=q, row(reg)=key. exp2 in-register, then packtrunc directly into the
//    PV B-operand (k=quad*8+j): regs [t_even r0..3 | t_odd r0..3].
//  - PV: out^T = V^T * P^T (A=V^T from Vs; C: col=q, row=d). Vs columns are
//    PRE-PERMUTED (by qkv's Vt epilogue) so B-frag key slots line up:
//    col 32C+8q'+4b+r holds key 32C+16b+4q'+r.
//  - l = sum(p) via constant ones A-frag (5th m-tile) — zero DS, zero VALU.
//  - Wave (qh,kh): q-rows qh*32..+31 (two 16-q n-tiles), keys kh*64..+63.
//    Cross-kh merge once at end through Ks-as-scratch; output transposed
//    through Vs-as-scratch for coalesced b128 stores.
// DS/wave-iter: 24 b128 (was 26 b128 + 16 b64). LDS = Ks 18.5K + Vs 16.8K
// = 35.3 KB -> 3 blocks/CU (launch_bounds(256,3)).
// ---------------------------------------------------------------------------
__global__ __launch_bounds__(256, 3) void attn_kernel(
    const unsigned short* Qb, const unsigned short* Kb,
    const unsigned short* Vt, unsigned short* ctx)
{
  __shared__ unsigned short Ks[128][74];   // [key][d], natural key order
  __shared__ unsigned short Vs[64][134];   // [d][permuted key]; Q at start

  const int tid  = threadIdx.x;
  const int wave = tid >> 6, lane = tid & 63;
  const int lrow = lane & 15, lgrp = lane >> 4;   // lgrp = quad
  const int qh = wave >> 1, kh = wave & 1;
  const int bh = blockIdx.y, b = bh >> 3, h = bh & 7;
  const int qbase = blockIdx.x * 64;

  const unsigned short* Qg  = Qb + (size_t)(b * 2048 + qbase) * 512 + h * 64;
  const unsigned short* Kg  = Kb + (size_t)(b * 2048) * 512 + h * 64;
  const unsigned short* Vtg = Vt + (size_t)bh * 64 * 2048;

  // stage Q (64x64) into Vs[0..63][0..63]; pull persistent B-frags
#pragma unroll
  for (int i = 0; i < 2; i++) {
    int seg = tid + i * 256;
    int row = seg >> 3, c0 = (seg & 7) * 8;
    *(uint4v*)&Vs[row][c0] = *(const uint4v*)(Qg + (size_t)row * 512 + c0);
  }
  __syncthreads();
  bf16x8 qf[2][2];
#pragma unroll
  for (int qt = 0; qt < 2; qt++)
#pragma unroll
    for (int ks = 0; ks < 2; ks++)
      qf[qt][ks] = *(const bf16x8*)&Vs[qh * 32 + qt * 16 + lrow][ks * 32 + lgrp * 8];

  bf16x8 vone;
  { uint4v o = (uint4v){0x3F803F80u, 0x3F803F80u, 0x3F803F80u, 0x3F803F80u};
    vone = as_bf(o); }

  // staging coords
  const int s0  = tid >> 3, kc_ = (tid & 7) * 8;   // K rows s0+32i (natural)
  const int vd0 = tid >> 4, vc_ = (tid & 15) * 8;  // V d-rows vd0+16i

  f32x4 oacc[2][5];                     // [qt][dt]; dt==4 is the l-row-block
#pragma unroll
  for (int qt = 0; qt < 2; qt++)
#pragma unroll
    for (int d = 0; d < 5; d++) oacc[qt][d] = (f32x4){0.f, 0.f, 0.f, 0.f};

  uint4v kr[4], vr[4];
#pragma unroll
  for (int i = 0; i < 4; i++) {         // prefetch iter 0
    kr[i] = *(const uint4v*)(Kg + (size_t)(s0 + 32 * i) * 512 + kc_);
    vr[i] = *(const uint4v*)(Vtg + (size_t)(vd0 + 16 * i) * 2048 + vc_);
  }
  __syncthreads();                      // Q frag reads done before overwrite

  for (int it = 0; it < 16; ++it) {
#pragma unroll
    for (int i = 0; i < 4; i++) {
      *(uint4v*)&Ks[s0 + 32 * i][kc_]  = kr[i];
      *(uint4v*)&Vs[vd0 + 16 * i][vc_] = vr[i];
    }
    __syncthreads();
    if (it < 15) {                      // prefetch next tile
      const int key0 = (it + 1) * 128;
#pragma unroll
      for (int i = 0; i < 4; i++) {
        kr[i] = *(const uint4v*)(Kg + (size_t)(key0 + s0 + 32 * i) * 512 + kc_);
        vr[i] = *(const uint4v*)(Vtg + (size_t)(vd0 + 16 * i) * 2048 + key0 + vc_);
      }
    }

    // S^T = K*Q^T over this wave's 64 keys x 32 q (4 key-tiles, 2 q-tiles)
    f32x4 sacc[2][4];
#pragma unroll
    for (int qt = 0; qt < 2; qt++)
#pragma unroll
      for (int kt = 0; kt < 4; kt++) sacc[qt][kt] = (f32x4){0.f, 0.f, 0.f, 0.f};
#pragma unroll
    for (int kt = 0; kt < 4; kt++) {
      bf16x8 a0 = *(const bf16x8*)&Ks[kh * 64 + kt * 16 + lrow][lgrp * 8];
      bf16x8 a1 = *(const bf16x8*)&Ks[kh * 64 + kt * 16 + lrow][32 + lgrp * 8];
#pragma unroll
      for (int qt = 0; qt < 2; qt++) {
        sacc[qt][kt] = __builtin_amdgcn_mfma_f32_16x16x32_bf16(a0, qf[qt][0], sacc[qt][kt], 0, 0, 0);
        sacc[qt][kt] = __builtin_amdgcn_mfma_f32_16x16x32_bf16(a1, qf[qt][1], sacc[qt][kt], 0, 0, 0);
      }
    }

    // p = exp2(s) in-register
#pragma unroll
    for (int qt = 0; qt < 2; qt++)
#pragma unroll
      for (int kt = 0; kt < 4; kt++)
#pragma unroll
        for (int r = 0; r < 4; r++)
          sacc[qt][kt][r] = __builtin_amdgcn_exp2f(sacc[qt][kt][r]);

    // PV: out^T += V^T * P^T ; P^T packed straight from sacc (no LDS!)
#pragma unroll
    for (int c = 0; c < 2; c++) {
      bf16x8 pf[2];
#pragma unroll
      for (int qt = 0; qt < 2; qt++) {
        uint4v pk;
        pk.x = packtrunc(sacc[qt][2 * c][0],     sacc[qt][2 * c][1]);
        pk.y = packtrunc(sacc[qt][2 * c][2],     sacc[qt][2 * c][3]);
        pk.z = packtrunc(sacc[qt][2 * c + 1][0], sacc[qt][2 * c + 1][1]);
        pk.w = packtrunc(sacc[qt][2 * c + 1][2], sacc[qt][2 * c + 1][3]);
        pf[qt] = as_bf(pk);
      }
#pragma unroll
      for (int dt = 0; dt < 5; dt++) {
        bf16x8 vb = (dt < 4)
          ? *(const bf16x8*)&Vs[dt * 16 + lrow][(2 * kh + c) * 32 + lgrp * 8]
          : vone;
#pragma unroll
        for (int qt = 0; qt < 2; qt++)
          oacc[qt][dt] = __builtin_amdgcn_mfma_f32_16x16x32_bf16(vb, pf[qt], oacc[qt][dt], 0, 0, 0);
      }
    }
    __syncthreads();                    // frag reads done before restage
  }

  // ---- cross-kh merge (through Ks scratch), then transpose via Vs scratch
  float* Obuf = (float*)&Ks[0][0];      // 64 x 68 fp32
  float* Lbuf = Obuf + 64 * 68;         // 64 fp32
  if (kh == 1) {
#pragma unroll
    for (int qt = 0; qt < 2; qt++) {
      int qrow = qh * 32 + qt * 16 + lrow;
#pragma unroll
      for (int dt = 0; dt < 4; dt++)
#pragma unroll
        for (int r = 0; r < 4; r++)
          Obuf[qrow * 68 + dt * 16 + lgrp * 4 + r] = oacc[qt][dt][r];
      if (lgrp == 0) Lbuf[qrow] = oacc[qt][4][0];
    }
  }
  __syncthreads();
  if (kh == 0) {
#pragma unroll
    for (int qt = 0; qt < 2; qt++) {
      int qrow = qh * 32 + qt * 16 + lrow;
      float inv = 1.0f / (oacc[qt][4][0] + Lbuf[qrow]);
#pragma unroll
      for (int dt = 0; dt < 4; dt++)
#pragma unroll
        for (int r = 0; r < 4; r++) {
          float val = (oacc[qt][dt][r] + Obuf[qrow * 68 + dt * 16 + lgrp * 4 + r]) * inv;
          Vs[qrow][dt * 16 + lgrp * 4 + r] = f2bf(val);
        }
    }
  }
  __syncthreads();
  // cooperative coalesced store of ctx tile (64 x 64 bf16)
  unsigned short* Cg = ctx + (size_t)(b * 2048 + qbase) * 512 + h * 64;
#pragma unroll
  for (int i = 0; i < 2; i++) {
    int seg = tid + i * 256;
    int row = seg >> 3, c0 = (seg & 7) * 8;
    *(uint4v*)(Cg + (size_t)row * 512 + c0) = *(const uint4v*)&Vs[row][c0];
  }
}

extern "C" void kernel_launch(void* const* d_in, const int* in_sizes, int n_in,
                              void* d_out, int out_size, void* d_ws, size_t ws_size,
                              hipStream_t stream)
{
  const float* q  = (const float*)d_in[0];
  const float* k  = (const float*)d_in[1];
  const float* v  = (const float*)d_in[2];
  const float* Wq = (const float*)d_in[3];
  const float* bq = (const float*)d_in[4];
  const float* Wk = (const float*)d_in[5];
  const float* bk = (const float*)d_in[6];
  const float* Wv = (const float*)d_in[7];
  const float* bv = (const float*)d_in[8];
  const float* Wo = (const float*)d_in[9];
  const float* bo = (const float*)d_in[10];
  float* out = (float*)d_out;

  unsigned short* wqc = (unsigned short*)d_ws;
  unsigned short* wkc = wqc + (1 << 18);
  unsigned short* wvc = wkc + (1 << 18);
  unsigned short* woc = wvc + (1 << 18);
  unsigned short* Qb  = woc + (1 << 18);
  unsigned short* Kb  = Qb  + (1 << 21);
  unsigned short* Vt  = Kb  + (1 << 21);
  unsigned short* Cb  = Vt  + (1 << 21);

  const float qscale = 0.125f * 1.44269504088896340736f;  // 1/sqrt(64)*log2e

  convert_w<<<dim3(128, 4), 256, 0, stream>>>(
      Wq, Wk, Wv, Wo, wqc, wkc, wvc, woc, qscale);
  qkv_gemm<<<dim3(4, 64, 3), 256, 0, stream>>>(
      q, k, v, wqc, wkc, wvc, bq, bk, bv, Qb, Kb, Vt, qscale);
  attn_kernel<<<dim3(32, 16), 256, 0, stream>>>(Qb, Kb, Vt, Cb);
  out_gemm<<<dim3(8, 64), 256, 0, stream>>>(Cb, woc, bo, out);
}